// Round 1
// baseline (772.184 us; speedup 1.0000x reference)
//
#include <hip/hip_runtime.h>
#include <hip/hip_bf16.h>
#include <stdint.h>

#define B_   64
#define N_   128
#define H_   256
#define FH   1024   // 4*H
#define NT   32     // trunks
#define TL   32     // trunk len
#define LV   3
#define OUT_ 10

typedef __attribute__((ext_vector_type(8))) short short8;
typedef __attribute__((ext_vector_type(4))) float f32x4;

__device__ inline float sigmoidf_(float x) { return 1.0f / (1.0f + __expf(-x)); }
__device__ inline float tanhf_(float x) { float t = __expf(2.0f * x); return 1.0f - 2.0f / (t + 1.0f); }
__device__ inline unsigned short f2bf(float x) {
    union { float f; unsigned u; } v; v.f = x;
    unsigned r = (v.u + 0x7FFFu + ((v.u >> 16) & 1u)) >> 16;
    return (unsigned short)r;
}

// prep 1: u[l][j] = W_ih[l][j,:] . W_enc ;  v[l][j] = W_ih[l][j,:] . b_enc + b_ih + b_hh
__global__ void prep_uv(const float* __restrict__ W_enc, const float* __restrict__ b_enc,
                        const float* __restrict__ W_ih, const float* __restrict__ b_ih,
                        const float* __restrict__ b_hh,
                        float* __restrict__ u, float* __restrict__ v) {
    int j = blockIdx.x;            // 0..3071  (l*1024 + jj)
    int lane = threadIdx.x;        // 0..63
    const float4 w  = ((const float4*)(W_ih + (size_t)j * H_))[lane];
    const float4 we = ((const float4*)W_enc)[lane];
    const float4 be = ((const float4*)b_enc)[lane];
    float du = w.x * we.x + w.y * we.y + w.z * we.z + w.w * we.w;
    float dv = w.x * be.x + w.y * be.y + w.z * be.z + w.w * be.w;
    for (int m = 32; m >= 1; m >>= 1) { du += __shfl_xor(du, m); dv += __shfl_xor(dv, m); }
    if (lane == 0) { u[j] = du; v[j] = dv + b_ih[j] + b_hh[j]; }
}

// prep 2: W_hh -> bf16 ; init out with sum_l b_lin
__global__ void prep_whh(const float* __restrict__ W_hh, unsigned short* __restrict__ whh_bf,
                         const float* __restrict__ b_lin, float* __restrict__ out) {
    int gid = blockIdx.x * blockDim.x + threadIdx.x;    // 0..196607, each converts 4
    const float4 w = ((const float4*)W_hh)[gid];
    ushort4 o;
    o.x = f2bf(w.x); o.y = f2bf(w.y); o.z = f2bf(w.z); o.w = f2bf(w.w);
    ((ushort4*)whh_bf)[gid] = o;
    if (gid < B_ * OUT_) {
        int oo = gid % OUT_;
        out[gid] = b_lin[oo] + b_lin[OUT_ + oo] + b_lin[2 * OUT_ + oo];
    }
}

__global__ __launch_bounds__(256, 1)
void lstm_main(const float* __restrict__ bfeat, const int* __restrict__ trunk_idx,
               const int* __restrict__ trunk_len,
               const unsigned short* __restrict__ whh_bf,
               const float* __restrict__ u, const float* __restrict__ v,
               const float* __restrict__ W_lin, float* __restrict__ out) {
    __shared__ __align__(16) unsigned short hbuf[32][264];   // bf16 h, +8 pad per row
    __shared__ __align__(16) float svals[32];
    __shared__ __align__(16) float hlast[32][260];           // fp32 h_last for epilogue

    const int bid = blockIdx.x;        // 192 blocks: l(3) x t(32) x half(2)
    const int l = bid >> 6;
    const int r = bid & 63;
    const int t = r >> 1;
    const int b0 = (r & 1) * 32;

    const int tid = threadIdx.x;
    const int w = tid >> 6;            // wave 0..3 -> h-slice [64w, 64w+64)
    const int lane = tid & 63;
    const int col = lane & 15;
    const int q = lane >> 4;

    const unsigned short* whh_l = whh_bf + (size_t)l * FH * H_;
    const float* u_l = u + l * FH;
    const float* v_l = v + l * FH;

    // per-lane u/v: wave w owns gate columns j = g*256 + w*64 + n*16 + col
    float u_r[4][4], v_r[4][4];
    #pragma unroll
    for (int g = 0; g < 4; ++g)
        #pragma unroll
        for (int n = 0; n < 4; ++n) {
            int j = g * 256 + w * 64 + n * 16 + col;
            u_r[g][n] = u_l[j];
            v_r[g][n] = v_l[j];
        }

    // zero h buffer (h0 = 0)
    unsigned short* hflat = &hbuf[0][0];
    for (int i = tid; i < 32 * 264; i += 256) hflat[i] = 0;

    f32x4 c_r[2][4];   // c state: [m_tile][n], 4 regs each (rows)
    f32x4 h_r[2][4];   // last h (fp32) for epilogue
    #pragma unroll
    for (int mt = 0; mt < 2; ++mt)
        #pragma unroll
        for (int n = 0; n < 4; ++n)
            #pragma unroll
            for (int rg = 0; rg < 4; ++rg) { c_r[mt][n][rg] = 0.0f; h_r[mt][n][rg] = 0.0f; }

    int len = trunk_len[l * NT + t];
    if (len < 1) len = 1;
    const int* tix = trunk_idx + (l * NT + t) * TL;

    for (int p = 0; p < len; ++p) {
        // per-step scalar inputs: s_m = batch_feature[b0+m, idx[l,t,p]]
        if (tid < 32) {
            int np = tix[p];
            svals[tid] = bfeat[(b0 + tid) * N_ + np];
        }
        __syncthreads();   // svals ready; prev-step hbuf writes visible

        f32x4 s_v[2];
        s_v[0] = *(const f32x4*)&svals[q * 4];        // m = mt*16 + q*4 + rg
        s_v[1] = *(const f32x4*)&svals[16 + q * 4];

        // A fragments: lane holds h[row=col][k = ks*32 + q*8 + 0..7]
        short8 a_f[2][8];
        #pragma unroll
        for (int mt = 0; mt < 2; ++mt)
            #pragma unroll
            for (int ks = 0; ks < 8; ++ks)
                a_f[mt][ks] = *(const short8*)&hbuf[mt * 16 + col][ks * 32 + q * 8];

        __syncthreads();   // all reads of old h done before anyone overwrites

        // accumulator init = gate_pre = s*u + v
        f32x4 acc[2][4][4];
        #pragma unroll
        for (int mt = 0; mt < 2; ++mt)
            #pragma unroll
            for (int g = 0; g < 4; ++g)
                #pragma unroll
                for (int n = 0; n < 4; ++n)
                    #pragma unroll
                    for (int rg = 0; rg < 4; ++rg)
                        acc[mt][g][n][rg] = s_v[mt][rg] * u_r[g][n] + v_r[g][n];

        // gates += h @ W_hh^T   (B streamed from L2, K-contiguous)
        #pragma unroll
        for (int g = 0; g < 4; ++g)
            #pragma unroll
            for (int n = 0; n < 4; ++n) {
                int j = g * 256 + w * 64 + n * 16 + col;
                const unsigned short* bp = whh_l + (size_t)j * H_ + q * 8;
                #pragma unroll
                for (int ks = 0; ks < 8; ++ks) {
                    short8 b_f = *(const short8*)(bp + ks * 32);
                    acc[0][g][n] = __builtin_amdgcn_mfma_f32_16x16x32_bf16(a_f[0][ks], b_f, acc[0][g][n], 0, 0, 0);
                    acc[1][g][n] = __builtin_amdgcn_mfma_f32_16x16x32_bf16(a_f[1][ks], b_f, acc[1][g][n], 0, 0, 0);
                }
            }

        // nonlinearities + state update; write new h (bf16) to LDS
        #pragma unroll
        for (int mt = 0; mt < 2; ++mt)
            #pragma unroll
            for (int n = 0; n < 4; ++n)
                #pragma unroll
                for (int rg = 0; rg < 4; ++rg) {
                    float iv = acc[mt][0][n][rg];
                    float fv = acc[mt][1][n][rg];
                    float gv = acc[mt][2][n][rg];
                    float ov = acc[mt][3][n][rg];
                    float si = sigmoidf_(iv);
                    float sf = sigmoidf_(fv);
                    float so = sigmoidf_(ov);
                    float tg = tanhf_(gv);
                    float cn = sf * c_r[mt][n][rg] + si * tg;
                    c_r[mt][n][rg] = cn;
                    float hn = so * tanhf_(cn);
                    h_r[mt][n][rg] = hn;
                    hbuf[mt * 16 + q * 4 + rg][w * 64 + n * 16 + col] = f2bf(hn);
                }
    }

    // epilogue: h_last (fp32) -> LDS, then project to OUT and atomically accumulate
    #pragma unroll
    for (int mt = 0; mt < 2; ++mt)
        #pragma unroll
        for (int n = 0; n < 4; ++n)
            #pragma unroll
            for (int rg = 0; rg < 4; ++rg)
                hlast[mt * 16 + q * 4 + rg][w * 64 + n * 16 + col] = h_r[mt][n][rg];
    __syncthreads();

    const float* wl = W_lin + l * H_ * OUT_;
    for (int task = tid; task < 32 * OUT_; task += 256) {
        int m = task / OUT_, o = task % OUT_;
        float s = 0.f;
        for (int k = 0; k < H_; ++k) s += hlast[m][k] * wl[k * OUT_ + o];
        atomicAdd(&out[(b0 + m) * OUT_ + o], s);
    }
}

extern "C" void kernel_launch(void* const* d_in, const int* in_sizes, int n_in,
                              void* d_out, int out_size, void* d_ws, size_t ws_size,
                              hipStream_t stream) {
    const float* bfeat = (const float*)d_in[0];
    const int*   tidx  = (const int*)d_in[1];
    const int*   tlen  = (const int*)d_in[2];
    const float* W_enc = (const float*)d_in[3];
    const float* b_enc = (const float*)d_in[4];
    const float* W_ih  = (const float*)d_in[5];
    const float* W_hh  = (const float*)d_in[6];
    const float* b_ih  = (const float*)d_in[7];
    const float* b_hh  = (const float*)d_in[8];
    const float* W_lin = (const float*)d_in[9];
    const float* b_lin = (const float*)d_in[10];
    float* out = (float*)d_out;

    // ws layout: [0, 1572864) W_hh bf16 ; u at 1572864 (12288 B) ; v after
    unsigned short* whh_bf = (unsigned short*)d_ws;
    float* u = (float*)((char*)d_ws + 1572864);
    float* v = (float*)((char*)d_ws + 1572864 + 12288);

    prep_uv<<<LV * FH, 64, 0, stream>>>(W_enc, b_enc, W_ih, b_ih, b_hh, u, v);
    prep_whh<<<768, 256, 0, stream>>>(W_hh, whh_bf, b_lin, out);
    lstm_main<<<LV * NT * 2, 256, 0, stream>>>(bfeat, tidx, tlen, whh_bf, u, v, W_lin, out);
}

// Round 2
// 704.274 us; speedup vs baseline: 1.0964x; 1.0964x over previous
//
#include <hip/hip_runtime.h>
#include <hip/hip_bf16.h>
#include <stdint.h>

#define B_   64
#define N_   128
#define H_   256
#define FH   1024   // 4*H
#define NT   32     // trunks
#define TL   32     // trunk len
#define LV   3
#define OUT_ 10

typedef __attribute__((ext_vector_type(8))) short short8;
typedef __attribute__((ext_vector_type(4))) float f32x4;
typedef unsigned long long ull;

__device__ inline float sigmoidf_(float x) { return 1.0f / (1.0f + __expf(-x)); }
__device__ inline float tanhf_(float x) { float t = __expf(2.0f * x); return 1.0f - 2.0f / (t + 1.0f); }
__device__ inline unsigned short f2bf(float x) {
    union { float f; unsigned u; } v; v.f = x;
    unsigned r = (v.u + 0x7FFFu + ((v.u >> 16) & 1u)) >> 16;
    return (unsigned short)r;
}
__device__ inline float bf2f(unsigned short b) {
    union { unsigned u; float f; } v; v.u = ((unsigned)b) << 16; return v.f;
}

// prep 1: u[l][j] = W_ih[l][j,:] . W_enc ;  v[l][j] = W_ih[l][j,:] . b_enc + b_ih + b_hh
__global__ void prep_uv(const float* __restrict__ W_enc, const float* __restrict__ b_enc,
                        const float* __restrict__ W_ih, const float* __restrict__ b_ih,
                        const float* __restrict__ b_hh,
                        float* __restrict__ u, float* __restrict__ v) {
    int j = blockIdx.x;            // 0..3071  (l*1024 + jj)
    int lane = threadIdx.x;        // 0..63
    const float4 w  = ((const float4*)(W_ih + (size_t)j * H_))[lane];
    const float4 we = ((const float4*)W_enc)[lane];
    const float4 be = ((const float4*)b_enc)[lane];
    float du = w.x * we.x + w.y * we.y + w.z * we.z + w.w * we.w;
    float dv = w.x * be.x + w.y * be.y + w.z * be.z + w.w * be.w;
    for (int m = 32; m >= 1; m >>= 1) { du += __shfl_xor(du, m); dv += __shfl_xor(dv, m); }
    if (lane == 0) { u[j] = du; v[j] = dv + b_ih[j] + b_hh[j]; }
}

// prep 2: W_hh -> bf16 ; init out with sum_l b_lin ; zero the exchange flags
__global__ void prep_whh(const float* __restrict__ W_hh, unsigned short* __restrict__ whh_bf,
                         const float* __restrict__ b_lin, float* __restrict__ out,
                         int* __restrict__ flags) {
    int gid = blockIdx.x * blockDim.x + threadIdx.x;    // 0..196607, each converts 4
    const float4 w = ((const float4*)W_hh)[gid];
    ushort4 o;
    o.x = f2bf(w.x); o.y = f2bf(w.y); o.z = f2bf(w.z); o.w = f2bf(w.w);
    ((ushort4*)whh_bf)[gid] = o;
    if (gid < B_ * OUT_) {
        int oo = gid % OUT_;
        out[gid] = b_lin[oo] + b_lin[OUT_ + oo] + b_lin[2 * OUT_ + oo];
    }
    if (gid < 192) flags[gid] = 0;
}

// Main: 192 blocks = 96 trunk-pairs x 2 column-halves. Block (pair, cb) computes
// h-cols [cb*128, cb*128+128) for all 64 batch rows; W_hh slice lives in REGISTERS
// (64 short8 B-fragments per lane). Halves exchanged per step via agent-scope
// atomics + step-counter flag.
__global__ __launch_bounds__(256, 1)
void lstm_main(const float* __restrict__ bfeat, const int* __restrict__ trunk_idx,
               const int* __restrict__ trunk_len,
               const unsigned short* __restrict__ whh_bf,
               const float* __restrict__ u, const float* __restrict__ v,
               const float* __restrict__ W_lin,
               unsigned short* __restrict__ hx, int* __restrict__ flags,
               float* __restrict__ out) {
    __shared__ __align__(16) unsigned short hbuf[64][264];   // full h (both halves), bf16
    __shared__ __align__(16) float svals[64];

    const int bid = blockIdx.x;
    const int q16 = bid & 15;
    const int r16 = bid >> 4;            // 0..11
    const int xcd = q16 & 7;
    const int cb  = q16 >> 3;            // column half
    const int pair = r16 * 8 + xcd;      // 0..95  (partner = bid ^ 8, same XCD heuristic)
    const int pbid = bid ^ 8;
    const int l = pair >> 5;
    const int t = pair & 31;

    const int tid = threadIdx.x;
    const int w = tid >> 6;              // wave 0..3
    const int lane = tid & 63;
    const int col = lane & 15;
    const int q = lane >> 4;

    const unsigned short* whh_l = whh_bf + (size_t)l * FH * H_;

    // ---- load this wave's W_hh slice into registers (held for whole kernel) ----
    // wave w owns gate cols j = g*256 + cb*128 + w*32 + n*16 + col, g=0..3, n=0..1
    short8 Breg[8][8];                   // [g*2+n][ks]  -> 256 VGPRs
    #pragma unroll
    for (int g = 0; g < 4; ++g)
        #pragma unroll
        for (int n = 0; n < 2; ++n) {
            int j = g * 256 + cb * 128 + w * 32 + n * 16 + col;
            const unsigned short* bp = whh_l + (size_t)j * H_ + q * 8;
            #pragma unroll
            for (int ks = 0; ks < 8; ++ks)
                Breg[g * 2 + n][ks] = *(const short8*)(bp + ks * 32);
        }

    float u_r[4][2], v_r[4][2];
    {
        const float* u_l = u + l * FH;
        const float* v_l = v + l * FH;
        #pragma unroll
        for (int g = 0; g < 4; ++g)
            #pragma unroll
            for (int n = 0; n < 2; ++n) {
                int j = g * 256 + cb * 128 + w * 32 + n * 16 + col;
                u_r[g][n] = u_l[j];
                v_r[g][n] = v_l[j];
            }
    }

    f32x4 c_r[4][2];                     // c state per (mt, n)
    f32x4 h_new[4][2];
    #pragma unroll
    for (int mt = 0; mt < 4; ++mt)
        #pragma unroll
        for (int n = 0; n < 2; ++n)
            #pragma unroll
            for (int rg = 0; rg < 4; ++rg) c_r[mt][n][rg] = 0.0f;

    int len = trunk_len[l * NT + t];
    if (len < 1) len = 1;
    const int* tix = trunk_idx + (l * NT + t) * TL;

    unsigned short* hx_own = hx + (size_t)bid * 8192;
    const unsigned short* hx_par = hx + (size_t)pbid * 8192;
    const int mrow = tid >> 2;           // exchange-copy mapping: 64 B / thread
    const int ccol = (tid & 3) * 32;

    for (int p = 0; p < len; ++p) {
        if (tid < 64) svals[tid] = bfeat[tid * N_ + tix[p]];

        if (p > 0) {
            // wait for partner's h^(p), pull its half into LDS
            while (__hip_atomic_load(&flags[pbid], __ATOMIC_ACQUIRE, __HIP_MEMORY_SCOPE_AGENT) < p) {}
            const ull* src = (const ull*)(hx_par + mrow * 128 + ccol);
            ull* dst = (ull*)&hbuf[mrow][(1 - cb) * 128 + ccol];
            #pragma unroll
            for (int i = 0; i < 8; ++i)
                dst[i] = __hip_atomic_load(&src[i], __ATOMIC_RELAXED, __HIP_MEMORY_SCOPE_AGENT);
        }
        __syncthreads();   // S1: svals + partner half visible

        f32x4 sv[4];
        #pragma unroll
        for (int mt = 0; mt < 4; ++mt) sv[mt] = *(const f32x4*)&svals[mt * 16 + q * 4];

        #pragma unroll
        for (int mt = 0; mt < 4; ++mt) {
            f32x4 acc[4][2];
            #pragma unroll
            for (int g = 0; g < 4; ++g)
                #pragma unroll
                for (int n = 0; n < 2; ++n)
                    #pragma unroll
                    for (int rg = 0; rg < 4; ++rg)
                        acc[g][n][rg] = sv[mt][rg] * u_r[g][n] + v_r[g][n];

            if (p > 0) {
                short8 a_f[8];
                #pragma unroll
                for (int ks = 0; ks < 8; ++ks)
                    a_f[ks] = *(const short8*)&hbuf[mt * 16 + col][ks * 32 + q * 8];
                #pragma unroll
                for (int g = 0; g < 4; ++g)
                    #pragma unroll
                    for (int n = 0; n < 2; ++n)
                        #pragma unroll
                        for (int ks = 0; ks < 8; ++ks)
                            acc[g][n] = __builtin_amdgcn_mfma_f32_16x16x32_bf16(
                                a_f[ks], Breg[g * 2 + n][ks], acc[g][n], 0, 0, 0);
            }

            #pragma unroll
            for (int n = 0; n < 2; ++n)
                #pragma unroll
                for (int rg = 0; rg < 4; ++rg) {
                    float si = sigmoidf_(acc[0][n][rg]);
                    float sf = sigmoidf_(acc[1][n][rg]);
                    float tg = tanhf_(acc[2][n][rg]);
                    float so = sigmoidf_(acc[3][n][rg]);
                    float cn = sf * c_r[mt][n][rg] + si * tg;
                    c_r[mt][n][rg] = cn;
                    h_new[mt][n][rg] = so * tanhf_(cn);
                }
        }
        __syncthreads();   // S2: everyone done reading old h

        #pragma unroll
        for (int mt = 0; mt < 4; ++mt)
            #pragma unroll
            for (int n = 0; n < 2; ++n)
                #pragma unroll
                for (int rg = 0; rg < 4; ++rg)
                    hbuf[mt * 16 + q * 4 + rg][cb * 128 + w * 32 + n * 16 + col] =
                        f2bf(h_new[mt][n][rg]);
        __syncthreads();   // S3: new own-half in LDS complete

        if (p + 1 < len) {
            // publish own half at agent scope, then raise flag
            ull* dst = (ull*)(hx_own + mrow * 128 + ccol);
            const ull* src = (const ull*)&hbuf[mrow][cb * 128 + ccol];
            #pragma unroll
            for (int i = 0; i < 8; ++i)
                __hip_atomic_store(&dst[i], src[i], __ATOMIC_RELAXED, __HIP_MEMORY_SCOPE_AGENT);
            __syncthreads();   // S4: all waves' stores drained (barrier implies vmcnt(0))
            if (tid == 0)
                __hip_atomic_store(&flags[bid], p + 1, __ATOMIC_RELEASE, __HIP_MEMORY_SCOPE_AGENT);
        }
    }

    // epilogue: project own half of h_last to OUT, accumulate
    const float* wl = W_lin + l * H_ * OUT_;
    for (int task = tid; task < B_ * OUT_; task += 256) {
        int m = task / OUT_, o = task % OUT_;
        float s = 0.f;
        for (int k = 0; k < 128; ++k)
            s += bf2f(hbuf[m][cb * 128 + k]) * wl[(cb * 128 + k) * OUT_ + o];
        atomicAdd(&out[m * OUT_ + o], s);
    }
}

extern "C" void kernel_launch(void* const* d_in, const int* in_sizes, int n_in,
                              void* d_out, int out_size, void* d_ws, size_t ws_size,
                              hipStream_t stream) {
    const float* bfeat = (const float*)d_in[0];
    const int*   tidx  = (const int*)d_in[1];
    const int*   tlen  = (const int*)d_in[2];
    const float* W_enc = (const float*)d_in[3];
    const float* b_enc = (const float*)d_in[4];
    const float* W_ih  = (const float*)d_in[5];
    const float* W_hh  = (const float*)d_in[6];
    const float* b_ih  = (const float*)d_in[7];
    const float* b_hh  = (const float*)d_in[8];
    const float* W_lin = (const float*)d_in[9];
    const float* b_lin = (const float*)d_in[10];
    float* out = (float*)d_out;

    // ws layout
    unsigned short* whh_bf = (unsigned short*)d_ws;                       // 1,572,864 B
    float* u = (float*)((char*)d_ws + 1572864);                           // 12,288 B
    float* v = (float*)((char*)d_ws + 1572864 + 12288);                   // 12,288 B
    unsigned short* hx = (unsigned short*)((char*)d_ws + 1597440);        // 3,145,728 B
    int* flags = (int*)((char*)d_ws + 1597440 + 3145728);                 // 768 B

    prep_uv<<<LV * FH, 64, 0, stream>>>(W_enc, b_enc, W_ih, b_ih, b_hh, u, v);
    prep_whh<<<768, 256, 0, stream>>>(W_hh, whh_bf, b_lin, out, flags);
    lstm_main<<<192, 256, 0, stream>>>(bfeat, tidx, tlen, whh_bf, u, v, W_lin, hx, flags, out);
}